// Round 8
// baseline (369.811 us; speedup 1.0000x reference)
//
#include <hip/hip_runtime.h>
#include <cstdint>
#include <cstddef>

typedef short bf16x8 __attribute__((ext_vector_type(8)));
typedef float f32x4 __attribute__((ext_vector_type(4)));
typedef unsigned short u16;
typedef u16 u16x8 __attribute__((ext_vector_type(8)));

#define GLD16(gptr, lptr)                                                            \
  __builtin_amdgcn_global_load_lds((const __attribute__((address_space(1))) void*)(gptr), \
                                   (__attribute__((address_space(3))) void*)(lptr), 16, 0, 0)

__device__ __forceinline__ u16 f2bf(float f) {
  union { float f; unsigned u; } v; v.f = f;
  unsigned r = v.u + 0x7FFF + ((v.u >> 16) & 1);
  return (u16)(r >> 16);
}
__device__ __forceinline__ float bf2f(u16 h) {
  union { unsigned u; float f; } v; v.u = ((unsigned)h) << 16;
  return v.f;
}

// read 8 contiguous bf16 from a [rows][64] bf16 LDS tile with XOR swizzle (attn)
__device__ __forceinline__ bf16x8 lds_read_sw64(const u16* base, int row, int col) {
  int byt = row * 128 + col * 2;
  byt ^= (row & 7) << 4;
  return *(const bf16x8*)((const char*)base + byt);
}

// ---------------------------------------------------------------------------
// Weight transpose + cast: out[c][r] = bf16(in[r][c]); R,C multiples of 32
// ---------------------------------------------------------------------------
__global__ __launch_bounds__(256) void transpose_cast(const float* __restrict__ in,
                                                      u16* __restrict__ out, int R, int C) {
  __shared__ float tile[32][33];
  const int tx = threadIdx.x, ty = threadIdx.y;
  const int c0 = blockIdx.x * 32, r0 = blockIdx.y * 32;
#pragma unroll
  for (int i = 0; i < 32; i += 8)
    tile[ty + i][tx] = in[(size_t)(r0 + ty + i) * C + c0 + tx];
  __syncthreads();
#pragma unroll
  for (int i = 0; i < 32; i += 8)
    out[(size_t)(c0 + ty + i) * R + r0 + tx] = f2bf(tile[tx][ty + i]);
}

// ---------------------------------------------------------------------------
// LayerNorm (D=1024): fp32 in -> bf16 out
// ---------------------------------------------------------------------------
__global__ __launch_bounds__(256) void layernorm_bf16(const float* __restrict__ X,
                                                      const float* __restrict__ g,
                                                      const float* __restrict__ be,
                                                      u16* __restrict__ out) {
  const int row = blockIdx.x, t = threadIdx.x;
  const int lane = t & 63, wave = t >> 6;
  const float* x = X + (size_t)row * 1024;
  __shared__ float part[4];
  float v[4]; float s = 0.f;
#pragma unroll
  for (int i = 0; i < 4; ++i) { v[i] = x[t + i * 256]; s += v[i]; }
#pragma unroll
  for (int o = 32; o >= 1; o >>= 1) s += __shfl_xor(s, o);
  if (lane == 0) part[wave] = s;
  __syncthreads();
  const float mu = (part[0] + part[1] + part[2] + part[3]) * (1.f / 1024.f);
  float d2 = 0.f;
#pragma unroll
  for (int i = 0; i < 4; ++i) { float d = v[i] - mu; d2 += d * d; }
#pragma unroll
  for (int o = 32; o >= 1; o >>= 1) d2 += __shfl_xor(d2, o);
  __syncthreads();
  if (lane == 0) part[wave] = d2;
  __syncthreads();
  const float var = (part[0] + part[1] + part[2] + part[3]) * (1.f / 1024.f);
  const float rstd = rsqrtf(var + 1e-5f);
#pragma unroll
  for (int i = 0; i < 4; ++i) {
    const int c = t + i * 256;
    out[(size_t)row * 1024 + c] = f2bf((v[i] - mu) * rstd * g[c] + be[c]);
  }
}

// ---------------------------------------------------------------------------
// Ring-3 BK=32 pipelined bf16 MFMA GEMM: C[M,N]=A[M,K]*Bt[N,K]^T+bias (+epi).
// THREE LDS K-tile buffers; per step:
//   vmwait(4) counted [stage(kt) landed, stage(kt+1)'s 4 loads stay in flight]
//   s_barrier  -> all waves' stage(kt) contributions visible
//   stage(kt+2) into buf (kt+2)%3  [its readers (tile kt-1) delivered reads
//   before reaching this barrier -> race-free]
//   12 ds_read_b128 (folded+XOR-swizzled, 0-conflict pattern of r6/r7)
//   setprio(1); MF*NF MFMA; setprio(0)
// Tile folding: [BM rows][32 cols] stored as [BM/2][64] (row r -> folded row
// r%(BM/2), col-half r/(BM/2)) so the proven 128B-row swizzle applies.
// ConfigA: BM=BN=256, 512 thr, waves 2x4 (wave 128x64), LDS 96KB.
// ConfigC: BM=BN=128, 256 thr, waves 2x2 (wave 64x64), LDS 48KB (3 blk/CU).
// EPI 0: bf16 out; EPI 1: f32 out = res+acc+bias; EPI 2: bf16 gelu(acc+bias)
// M%BM==0, N%BN==0, K%32==0, K>=96; grid multiple of 8.
// ---------------------------------------------------------------------------
template <int EPI, int BM, int BN, int TPB, int WM, int WN>
__global__ __launch_bounds__(TPB) void gemm_p(const u16* __restrict__ A,
                                              const u16* __restrict__ Bt,
                                              const float* __restrict__ bias,
                                              const float* __restrict__ res,
                                              float* __restrict__ outf,
                                              u16* __restrict__ outb,
                                              int M, int N, int K) {
  constexpr int WR = BM / WM, WC = BN / WN;
  constexpr int MF = WR / 16, NF = WC / 16;
  constexpr int ASZ = BM * 64, BSZ = BN * 64;   // bytes per K-tile buffer
  constexpr int NLD = (BM * 64) / (TPB * 16);   // =2 for both configs
  __shared__ __attribute__((aligned(16))) char lds[3 * (ASZ + BSZ)];

  const int t = threadIdx.x, lane = t & 63, wave = t >> 6;
  const int wm = wave / WN, wn = wave % WN;
  const int l15 = lane & 15, l16 = lane >> 4;

  const int lb = ((int)blockIdx.x & 7) * ((int)gridDim.x >> 3) + ((int)blockIdx.x >> 3);
  const int NBN = N / BN;
  const int bm = (lb / NBN) * BM, bn = (lb % NBN) * BN;

  // staging sources, pre-permuted by the fold+swizzle involution:
  // dest-linear byte d -> folded row r2=d>>7, 16B slot ((d>>4)&7)^(r2&7);
  // source row = r2 + (slot>>2)*(half), source col elems = (slot&3)*8.
  const u16* aptr[NLD];
  const u16* bptr[NLD];
#pragma unroll
  for (int c = 0; c < NLD; ++c) {
    const int d = c * TPB * 16 + t * 16;
    const int r2 = d >> 7;
    const int sl = ((d >> 4) & 7) ^ (r2 & 7);
    aptr[c] = A + (size_t)(bm + r2 + (sl >> 2) * (BM / 2)) * K + (sl & 3) * 8;
    bptr[c] = Bt + (size_t)(bn + r2 + (sl >> 2) * (BN / 2)) * K + (sl & 3) * 8;
  }

  auto stage = [&](int p) {
    const int ko = p * 32;
    const int s = p % 3;
    char* ab = lds + s * ASZ + t * 16;
    char* bb = lds + 3 * ASZ + s * BSZ + t * 16;
#pragma unroll
    for (int c = 0; c < NLD; ++c) GLD16(aptr[c] + ko, ab + c * TPB * 16);
#pragma unroll
    for (int c = 0; c < NLD; ++c) GLD16(bptr[c] + ko, bb + c * TPB * 16);
  };
  stage(0); stage(1);

  // read offsets (folded layout): A row r=wm*WR+m*16+l15 -> hi=wm (WR==BM/2),
  // folded row m*16+l15; col-part = hi*64 + l16*16, XOR (l15&7)<<4.
  const int sw = (l15 & 7) << 4;
  const int acol = (wm * 64 + l16 * 16) ^ sw;
  constexpr int HB = BN / 2;
  const int hiB = (wn * WC) / HB;
  const int fB0 = (wn * WC) % HB;
  const int bcol = (hiB * 64 + l16 * 16) ^ sw;

  f32x4 acc[MF][NF] = {};
  const int nkt = K >> 5;

#pragma unroll 1
  for (int kt = 0; kt < nkt; ++kt) {
    if (kt < nkt - 1) asm volatile("s_waitcnt vmcnt(4)" ::: "memory");
    else              asm volatile("s_waitcnt vmcnt(0)" ::: "memory");
    asm volatile("s_barrier" ::: "memory");
    if (kt + 2 < nkt) stage(kt + 2);

    const int s = kt % 3;
    const char* ab = lds + s * ASZ;
    const char* bb = lds + 3 * ASZ + s * BSZ;
    bf16x8 a[MF], b[NF];
#pragma unroll
    for (int m = 0; m < MF; ++m)
      a[m] = *(const bf16x8*)(ab + (m * 16 + l15) * 128 + acol);
#pragma unroll
    for (int n = 0; n < NF; ++n)
      b[n] = *(const bf16x8*)(bb + (fB0 + n * 16 + l15) * 128 + bcol);
    __builtin_amdgcn_s_setprio(1);
#pragma unroll
    for (int m = 0; m < MF; ++m)
#pragma unroll
      for (int n = 0; n < NF; ++n)
        acc[m][n] = __builtin_amdgcn_mfma_f32_16x16x32_bf16(a[m], b[n], acc[m][n], 0, 0, 0);
    __builtin_amdgcn_s_setprio(0);
  }

  const int r0 = l16 * 4;
#pragma unroll
  for (int m = 0; m < MF; ++m) {
#pragma unroll
    for (int n = 0; n < NF; ++n) {
      const int col = bn + wn * WC + n * 16 + l15;
      const float bv = bias[col];
#pragma unroll
      for (int r = 0; r < 4; ++r) {
        const int row = bm + wm * WR + m * 16 + r0 + r;
        const float v = acc[m][n][r] + bv;
        const size_t o = (size_t)row * N + col;
        if (EPI == 0) {
          outb[o] = f2bf(v);
        } else if (EPI == 1) {
          outf[o] = res[o] + v;
        } else {
          // tanh-form GELU (|err| ~3e-4, well under threshold)
          const float u = 0.7978845608f * (v + 0.044715f * v * v * v);
          const float e = __expf(2.f * u);
          const float th = 1.f - 2.f / (1.f + e);
          outb[o] = f2bf(0.5f * v * (1.f + th));
        }
      }
    }
  }
}

// ---------------------------------------------------------------------------
// Attention scores + softmax -> probs (bf16). grid(4 qblk, 16 h, 32 b), 256 thr
// probs layout: [b][h][q][k] = [((b*16+h)*256+q)*256+k]
// ---------------------------------------------------------------------------
__global__ __launch_bounds__(256) void attn_scores(const u16* __restrict__ qkv,
                                                   u16* __restrict__ probs) {
  __shared__ u16 Ks[256 * 64];  // 32KB swizzled
  __shared__ u16 Qs[64 * 64];   //  8KB swizzled
  const int t = threadIdx.x, lane = t & 63, wave = t >> 6;
  const int qb = blockIdx.x * 64, h = blockIdx.y, b = blockIdx.z;
  const size_t row0 = (size_t)b * 256 * 3072;

#pragma unroll
  for (int is = 0; is < 8; ++is) {
    int L = (is * 2048 + t * 8) * 2;
    int x = (L ^ ((L >> 3) & 0x70)) >> 1;
    int kk = x >> 6, d = x & 63;
    const u16* gp = qkv + row0 + (size_t)kk * 3072 + 1024 + h * 64 + d;
    GLD16(gp, (char*)Ks + is * 4096 + wave * 1024);
  }
#pragma unroll
  for (int is = 0; is < 2; ++is) {
    int L = (is * 2048 + t * 8) * 2;
    int x = (L ^ ((L >> 3) & 0x70)) >> 1;
    int q = x >> 6, d = x & 63;
    const u16* gp = qkv + row0 + (size_t)(qb + q) * 3072 + h * 64 + d;
    GLD16(gp, (char*)Qs + is * 4096 + wave * 1024);
  }
  __syncthreads();

  f32x4 acc[16] = {};
  bf16x8 aq[2];
#pragma unroll
  for (int ks = 0; ks < 2; ++ks)
    aq[ks] = lds_read_sw64(Qs, wave * 16 + (lane & 15), ks * 32 + (lane >> 4) * 8);
#pragma unroll
  for (int nf = 0; nf < 16; ++nf) {
#pragma unroll
    for (int ks = 0; ks < 2; ++ks) {
      bf16x8 bk = lds_read_sw64(Ks, nf * 16 + (lane & 15), ks * 32 + (lane >> 4) * 8);
      acc[nf] = __builtin_amdgcn_mfma_f32_16x16x32_bf16(aq[ks], bk, acc[nf], 0, 0, 0);
    }
  }

  const int r0 = (lane >> 4) * 4, cc = lane & 15;
  const float sc = 0.125f;  // 1/sqrt(64)
#pragma unroll
  for (int r = 0; r < 4; ++r) {
    float mx = -1e30f;
#pragma unroll
    for (int nf = 0; nf < 16; ++nf) mx = fmaxf(mx, acc[nf][r]);
#pragma unroll
    for (int o = 8; o >= 1; o >>= 1) mx = fmaxf(mx, __shfl_xor(mx, o));
    float s = 0.f;
#pragma unroll
    for (int nf = 0; nf < 16; ++nf) {
      float e = __expf((acc[nf][r] - mx) * sc);
      acc[nf][r] = e; s += e;
    }
#pragma unroll
    for (int o = 8; o >= 1; o >>= 1) s += __shfl_xor(s, o);
    const float rinv = 1.f / s;
    const int qrow = qb + wave * 16 + r0 + r;
    u16* prow = probs + (size_t)((b * 16 + h) * 256 + qrow) * 256;
#pragma unroll
    for (int nf = 0; nf < 16; ++nf)
      prow[nf * 16 + cc] = f2bf(acc[nf][r] * rinv);
  }
}

// ---------------------------------------------------------------------------
// A = mean over heads of probs. grid(8192=b*256+q), 256 thr
// ---------------------------------------------------------------------------
__global__ __launch_bounds__(256) void amean(const u16* __restrict__ probs,
                                             float* __restrict__ A) {
  const int bq = blockIdx.x;
  const int b = bq >> 8, q = bq & 255;
  const int t = threadIdx.x;
  float s = 0.f;
#pragma unroll
  for (int h = 0; h < 16; ++h)
    s += bf2f(probs[(size_t)((b * 16 + h) * 256 + q) * 256 + t]);
  A[(size_t)bq * 256 + t] = s * (1.f / 16.f);
}

// ---------------------------------------------------------------------------
// PV: ctx[b,:,h*64:+64] = probs[b,h] @ V[b,h]. grid(16 h, 32 b), 256 thr
// ---------------------------------------------------------------------------
__global__ __launch_bounds__(256) void attn_pv(const u16* __restrict__ qkv,
                                               const u16* __restrict__ probs,
                                               u16* __restrict__ ctx) {
  __shared__ u16 Vs[64 * 256];  // 32KB: [d][kk], swizzled
  const int t = threadIdx.x, lane = t & 63, wave = t >> 6;
  const int h = blockIdx.x, b = blockIdx.y;

#pragma unroll
  for (int p = 0; p < 8; ++p) {
    int idx = p * 2048 + t * 8;
    int kk = idx >> 6, d0 = idx & 63;
    u16x8 vv = *(const u16x8*)(qkv + (size_t)(b * 256 + kk) * 3072 + 2048 + h * 64 + d0);
#pragma unroll
    for (int j = 0; j < 8; ++j) {
      int d = d0 + j;
      int byt = (d * 512 + kk * 2) ^ ((d & 7) << 4);
      *(u16*)((char*)Vs + byt) = vv[j];
    }
  }
  __syncthreads();

  f32x4 acc[4][4] = {};
  const u16* Pb = probs + (size_t)((b * 16 + h) * 256) * 256;
  const int cc = lane & 15, kg = (lane >> 4) * 8;
#pragma unroll
  for (int kt = 0; kt < 8; ++kt) {
    bf16x8 a[4], v[4];
#pragma unroll
    for (int m = 0; m < 4; ++m)
      a[m] = *(const bf16x8*)(Pb + (size_t)(wave * 64 + m * 16 + cc) * 256 + kt * 32 + kg);
#pragma unroll
    for (int n = 0; n < 4; ++n) {
      int d = n * 16 + cc;
      int kk = kt * 32 + kg;
      int byt = (d * 512 + kk * 2) ^ ((d & 7) << 4);
      v[n] = *(const bf16x8*)((const char*)Vs + byt);
    }
#pragma unroll
    for (int m = 0; m < 4; ++m)
#pragma unroll
      for (int n = 0; n < 4; ++n)
        acc[m][n] = __builtin_amdgcn_mfma_f32_16x16x32_bf16(a[m], v[n], acc[m][n], 0, 0, 0);
  }

  const int r0 = (lane >> 4) * 4;
#pragma unroll
  for (int m = 0; m < 4; ++m) {
    const int q = wave * 64 + m * 16 + r0;
#pragma unroll
    for (int n = 0; n < 4; ++n) {
      const int col = h * 64 + n * 16 + cc;
#pragma unroll
      for (int r = 0; r < 4; ++r)
        ctx[(size_t)(b * 256 + q + r) * 1024 + col] = f2bf(acc[m][n][r]);
    }
  }
}

// ---------------------------------------------------------------------------
extern "C" void kernel_launch(void* const* d_in, const int* in_sizes, int n_in,
                              void* d_out, int out_size, void* d_ws, size_t ws_size,
                              hipStream_t stream) {
  const float* X      = (const float*)d_in[0];
  const float* W_qkv  = (const float*)d_in[1];
  const float* b_qkv  = (const float*)d_in[2];
  const float* W_proj = (const float*)d_in[3];
  const float* b_proj = (const float*)d_in[4];
  const float* g1     = (const float*)d_in[5];
  const float* beta1  = (const float*)d_in[6];
  const float* g2     = (const float*)d_in[7];
  const float* beta2  = (const float*)d_in[8];
  const float* W_ff1  = (const float*)d_in[9];
  const float* b_ff1  = (const float*)d_in[10];
  const float* W_ff2  = (const float*)d_in[11];
  const float* b_ff2  = (const float*)d_in[12];

  float* Xout = (float*)d_out;                 // [8192][1024]
  float* Aout = (float*)d_out + 8388608;       // [32][256][256]

  char* ws = (char*)d_ws;
  const size_t MB = 1u << 20;
  u16* xn    = (u16*)(ws + 0);          // 16MB: Xn, then ctx, then X1n
  u16* wqkv  = (u16*)(ws + 16 * MB);    // 6MB [3072][1024]
  u16* wproj = (u16*)(ws + 22 * MB);    // 2MB [1024][1024]
  u16* wff1  = (u16*)(ws + 24 * MB);    // 8MB [4096][1024]
  u16* wff2  = (u16*)(ws + 32 * MB);    // 8MB [1024][4096]
  u16* qkv   = (u16*)(ws + 40 * MB);    // 48MB [8192][3072]
  u16* probs = (u16*)(ws + 88 * MB);    // 64MB [32][16][256][256]; later h
  u16* hbuf  = probs;                   // 64MB [8192][4096]
  float* x1  = (float*)(ws + 152 * MB); // 32MB [8192][1024]  (total 184MB)
  u16* ctx   = xn;                      // reuse region 0 after QKV GEMM
  u16* x1n   = xn;                      // reuse region 0 after proj GEMM

  const dim3 tb(32, 8);
  transpose_cast<<<dim3(96, 32),  tb, 0, stream>>>(W_qkv,  wqkv, 1024, 3072);
  transpose_cast<<<dim3(32, 32),  tb, 0, stream>>>(W_proj, wproj, 1024, 1024);
  transpose_cast<<<dim3(128, 32), tb, 0, stream>>>(W_ff1,  wff1, 1024, 4096);
  transpose_cast<<<dim3(32, 128), tb, 0, stream>>>(W_ff2,  wff2, 4096, 1024);

  layernorm_bf16<<<8192, 256, 0, stream>>>(X, g1, beta1, xn);

  // QKV: ConfigA (256x256, 8 waves). Grid 32x12 = 384 blocks.
  gemm_p<0, 256, 256, 512, 2, 4><<<384, 512, 0, stream>>>(
      xn, wqkv, b_qkv, nullptr, nullptr, qkv, 8192, 3072, 1024);

  attn_scores<<<dim3(4, 16, 32), 256, 0, stream>>>(qkv, probs);
  amean<<<8192, 256, 0, stream>>>(probs, Aout);
  attn_pv<<<dim3(16, 32), 256, 0, stream>>>(qkv, probs, ctx);

  // proj + residual: ConfigC (128x128, 4 waves). Grid 64x8 = 512 blocks.
  gemm_p<1, 128, 128, 256, 2, 2><<<512, 256, 0, stream>>>(
      ctx, wproj, b_proj, X, x1, nullptr, 8192, 1024, 1024);

  layernorm_bf16<<<8192, 256, 0, stream>>>(x1, g2, beta2, x1n);

  // FF1 + GELU: ConfigA. Grid 32x16 = 512 blocks.
  gemm_p<2, 256, 256, 512, 2, 4><<<512, 512, 0, stream>>>(
      x1n, wff1, b_ff1, nullptr, nullptr, hbuf, 8192, 4096, 1024);

  // FF2 + residual: ConfigC. Grid 64x8 = 512 blocks.
  gemm_p<1, 128, 128, 256, 2, 2><<<512, 256, 0, stream>>>(
      hbuf, wff2, b_ff2, x1, Xout, nullptr, 8192, 1024, 4096);
}

// Round 10
// 336.727 us; speedup vs baseline: 1.0983x; 1.0983x over previous
//
#include <hip/hip_runtime.h>
#include <cstdint>
#include <cstddef>

typedef short bf16x8 __attribute__((ext_vector_type(8)));
typedef float f32x4 __attribute__((ext_vector_type(4)));
typedef unsigned short u16;
typedef u16 u16x8 __attribute__((ext_vector_type(8)));

#define GLD16(gptr, lptr)                                                            \
  __builtin_amdgcn_global_load_lds((const __attribute__((address_space(1))) void*)(gptr), \
                                   (__attribute__((address_space(3))) void*)(lptr), 16, 0, 0)

__device__ __forceinline__ u16 f2bf(float f) {
  union { float f; unsigned u; } v; v.f = f;
  unsigned r = v.u + 0x7FFF + ((v.u >> 16) & 1);
  return (u16)(r >> 16);
}
__device__ __forceinline__ float bf2f(u16 h) {
  union { unsigned u; float f; } v; v.u = ((unsigned)h) << 16;
  return v.f;
}

// read 8 contiguous bf16 from a [rows][64] bf16 LDS tile with XOR swizzle (attn)
__device__ __forceinline__ bf16x8 lds_read_sw64(const u16* base, int row, int col) {
  int byt = row * 128 + col * 2;
  byt ^= (row & 7) << 4;
  return *(const bf16x8*)((const char*)base + byt);
}

// ---------------------------------------------------------------------------
// Weight transpose + cast: out[c][r] = bf16(in[r][c]); R,C multiples of 32
// ---------------------------------------------------------------------------
__global__ __launch_bounds__(256) void transpose_cast(const float* __restrict__ in,
                                                      u16* __restrict__ out, int R, int C) {
  __shared__ float tile[32][33];
  const int tx = threadIdx.x, ty = threadIdx.y;
  const int c0 = blockIdx.x * 32, r0 = blockIdx.y * 32;
#pragma unroll
  for (int i = 0; i < 32; i += 8)
    tile[ty + i][tx] = in[(size_t)(r0 + ty + i) * C + c0 + tx];
  __syncthreads();
#pragma unroll
  for (int i = 0; i < 32; i += 8)
    out[(size_t)(c0 + ty + i) * R + r0 + tx] = f2bf(tile[tx][ty + i]);
}

// ---------------------------------------------------------------------------
// LayerNorm (D=1024): fp32 in -> bf16 out
// ---------------------------------------------------------------------------
__global__ __launch_bounds__(256) void layernorm_bf16(const float* __restrict__ X,
                                                      const float* __restrict__ g,
                                                      const float* __restrict__ be,
                                                      u16* __restrict__ out) {
  const int row = blockIdx.x, t = threadIdx.x;
  const int lane = t & 63, wave = t >> 6;
  const float* x = X + (size_t)row * 1024;
  __shared__ float part[4];
  float v[4]; float s = 0.f;
#pragma unroll
  for (int i = 0; i < 4; ++i) { v[i] = x[t + i * 256]; s += v[i]; }
#pragma unroll
  for (int o = 32; o >= 1; o >>= 1) s += __shfl_xor(s, o);
  if (lane == 0) part[wave] = s;
  __syncthreads();
  const float mu = (part[0] + part[1] + part[2] + part[3]) * (1.f / 1024.f);
  float d2 = 0.f;
#pragma unroll
  for (int i = 0; i < 4; ++i) { float d = v[i] - mu; d2 += d * d; }
#pragma unroll
  for (int o = 32; o >= 1; o >>= 1) d2 += __shfl_xor(d2, o);
  __syncthreads();
  if (lane == 0) part[wave] = d2;
  __syncthreads();
  const float var = (part[0] + part[1] + part[2] + part[3]) * (1.f / 1024.f);
  const float rstd = rsqrtf(var + 1e-5f);
#pragma unroll
  for (int i = 0; i < 4; ++i) {
    const int c = t + i * 256;
    out[(size_t)row * 1024 + c] = f2bf((v[i] - mu) * rstd * g[c] + be[c]);
  }
}

// ---------------------------------------------------------------------------
// Ring-2 single-barrier 128x128 bf16 MFMA GEMM (2 blocks/CU for cross-block
// overlap per m114): C[M,N]=A[M,K]*Bt[N,K]^T+bias (+epi).
// 4 waves (2x2), wave 64x64, BK=64, LDS 64KB. Per K-step:
//   vmcnt(0); s_barrier; stage(kt+1); ks-outer {8 ds_read_b128; 16 MFMA}.
// Staging: 4 GLD16 per operand per thread (4 x 256thr x 16B = 16KB = full
// tile; r9 had 2 -> half-uninitialized LDS -> NaN).
// XCD grouping: 8bm x 8bn = 64 blocks co-resident per XCD (2/CU x 32 CU).
// XOR-swizzled LDS, 0 bank conflicts (measured r5-r8).
// EPI 0: bf16 out; EPI 1: f32 out = res+acc+bias; EPI 2: bf16 gelu(acc+bias)
// M%1024==0, N%1024==0, K%64==0; grid=(M/128)*(N/128) %8==0.
// ---------------------------------------------------------------------------
template <int EPI>
__global__ __launch_bounds__(256, 2) void gemm_128(const u16* __restrict__ A,
                                                   const u16* __restrict__ Bt,
                                                   const float* __restrict__ bias,
                                                   const float* __restrict__ res,
                                                   float* __restrict__ outf,
                                                   u16* __restrict__ outb,
                                                   int M, int N, int K) {
  constexpr int ABYT = 128 * 128;   // 16KB per K-tile per operand
  __shared__ __attribute__((aligned(16))) char lds[4 * ABYT];  // 64KB

  const int t = threadIdx.x, lane = t & 63, wave = t >> 6;
  const int wm = wave >> 1, wn = wave & 1;
  const int l15 = lane & 15, l16 = lane >> 4;

  // 8bm x 8bn grouping; bids ≡ xcd (mod 8) in one contiguous window
  const int xcd = (int)blockIdx.x & 7, q = (int)blockIdx.x >> 3;
  const int j = q & 63, gq = q >> 6;
  const int g = gq * 8 + xcd;
  const int NGN = N >> 10;          // N/(128*8)
  const int gm = g / NGN, gn = g % NGN;
  const int bm = (gm * 8 + (j >> 3)) * 128;
  const int bn = (gn * 8 + (j & 7)) * 128;

  // pre-swizzled staging sources: linear LDS dest + swizzled read = identity
  const u16* aptr[4];
  const u16* bptr[4];
#pragma unroll
  for (int c = 0; c < 4; ++c) {
    int Lb = c * 4096 + t * 16;
    int x = (Lb ^ ((Lb >> 3) & 0x70)) >> 1;
    aptr[c] = A + (size_t)(bm + (x >> 6)) * K + (x & 63);
    bptr[c] = Bt + (size_t)(bn + (x >> 6)) * K + (x & 63);
  }

  auto stage = [&](int p) {
    const int ko = p * 64;
    const int s = p & 1;
    char* ab = lds + s * ABYT + t * 16;
    char* bb = lds + 2 * ABYT + s * ABYT + t * 16;
#pragma unroll
    for (int c = 0; c < 4; ++c) GLD16(aptr[c] + ko, ab + c * 4096);
#pragma unroll
    for (int c = 0; c < 4; ++c) GLD16(bptr[c] + ko, bb + c * 4096);
  };
  stage(0);

  const int co0 = l16 * 16, co1 = 64 + l16 * 16;
  f32x4 acc[4][4] = {};
  const int nkt = K >> 6;

#pragma unroll 1
  for (int kt = 0; kt < nkt; ++kt) {
    asm volatile("s_waitcnt vmcnt(0)" ::: "memory");
    asm volatile("s_barrier" ::: "memory");
    if (kt + 1 < nkt) stage(kt + 1);

    const int s = kt & 1;
    const char* ab = lds + s * ABYT;
    const char* bb = lds + 2 * ABYT + s * ABYT;
#pragma unroll
    for (int ks = 0; ks < 2; ++ks) {
      const int co = ks ? co1 : co0;
      bf16x8 a[4], b[4];
#pragma unroll
      for (int m = 0; m < 4; ++m) {
        const int r = wm * 64 + m * 16 + l15;
        a[m] = *(const bf16x8*)(ab + r * 128 + (co ^ ((r & 7) << 4)));
      }
#pragma unroll
      for (int n = 0; n < 4; ++n) {
        const int r = wn * 64 + n * 16 + l15;
        b[n] = *(const bf16x8*)(bb + r * 128 + (co ^ ((r & 7) << 4)));
      }
      __builtin_amdgcn_s_setprio(1);
#pragma unroll
      for (int m = 0; m < 4; ++m)
#pragma unroll
        for (int n = 0; n < 4; ++n)
          acc[m][n] = __builtin_amdgcn_mfma_f32_16x16x32_bf16(a[m], b[n], acc[m][n], 0, 0, 0);
      __builtin_amdgcn_s_setprio(0);
    }
  }

  const int r0 = l16 * 4;
#pragma unroll
  for (int m = 0; m < 4; ++m) {
#pragma unroll
    for (int n = 0; n < 4; ++n) {
      const int col = bn + wn * 64 + n * 16 + l15;
      const float bv = bias[col];
#pragma unroll
      for (int r = 0; r < 4; ++r) {
        const int row = bm + wm * 64 + m * 16 + r0 + r;
        const float v = acc[m][n][r] + bv;
        const size_t o = (size_t)row * N + col;
        if (EPI == 0) {
          outb[o] = f2bf(v);
        } else if (EPI == 1) {
          outf[o] = res[o] + v;
        } else {
          // tanh-form GELU (|err| ~3e-4, well under threshold)
          const float u = 0.7978845608f * (v + 0.044715f * v * v * v);
          const float e = __expf(2.f * u);
          const float th = 1.f - 2.f / (1.f + e);
          outb[o] = f2bf(0.5f * v * (1.f + th));
        }
      }
    }
  }
}

// ---------------------------------------------------------------------------
// Attention scores + softmax -> probs (bf16). grid(4 qblk, 16 h, 32 b), 256 thr
// probs layout: [b][h][q][k] = [((b*16+h)*256+q)*256+k]
// ---------------------------------------------------------------------------
__global__ __launch_bounds__(256) void attn_scores(const u16* __restrict__ qkv,
                                                   u16* __restrict__ probs) {
  __shared__ u16 Ks[256 * 64];  // 32KB swizzled
  __shared__ u16 Qs[64 * 64];   //  8KB swizzled
  const int t = threadIdx.x, lane = t & 63, wave = t >> 6;
  const int qb = blockIdx.x * 64, h = blockIdx.y, b = blockIdx.z;
  const size_t row0 = (size_t)b * 256 * 3072;

#pragma unroll
  for (int is = 0; is < 8; ++is) {
    int L = (is * 2048 + t * 8) * 2;
    int x = (L ^ ((L >> 3) & 0x70)) >> 1;
    int kk = x >> 6, d = x & 63;
    const u16* gp = qkv + row0 + (size_t)kk * 3072 + 1024 + h * 64 + d;
    GLD16(gp, (char*)Ks + is * 4096 + wave * 1024);
  }
#pragma unroll
  for (int is = 0; is < 2; ++is) {
    int L = (is * 2048 + t * 8) * 2;
    int x = (L ^ ((L >> 3) & 0x70)) >> 1;
    int q = x >> 6, d = x & 63;
    const u16* gp = qkv + row0 + (size_t)(qb + q) * 3072 + h * 64 + d;
    GLD16(gp, (char*)Qs + is * 4096 + wave * 1024);
  }
  __syncthreads();

  f32x4 acc[16] = {};
  bf16x8 aq[2];
#pragma unroll
  for (int ks = 0; ks < 2; ++ks)
    aq[ks] = lds_read_sw64(Qs, wave * 16 + (lane & 15), ks * 32 + (lane >> 4) * 8);
#pragma unroll
  for (int nf = 0; nf < 16; ++nf) {
#pragma unroll
    for (int ks = 0; ks < 2; ++ks) {
      bf16x8 bk = lds_read_sw64(Ks, nf * 16 + (lane & 15), ks * 32 + (lane >> 4) * 8);
      acc[nf] = __builtin_amdgcn_mfma_f32_16x16x32_bf16(aq[ks], bk, acc[nf], 0, 0, 0);
    }
  }

  const int r0 = (lane >> 4) * 4, cc = lane & 15;
  const float sc = 0.125f;  // 1/sqrt(64)
#pragma unroll
  for (int r = 0; r < 4; ++r) {
    float mx = -1e30f;
#pragma unroll
    for (int nf = 0; nf < 16; ++nf) mx = fmaxf(mx, acc[nf][r]);
#pragma unroll
    for (int o = 8; o >= 1; o >>= 1) mx = fmaxf(mx, __shfl_xor(mx, o));
    float s = 0.f;
#pragma unroll
    for (int nf = 0; nf < 16; ++nf) {
      float e = __expf((acc[nf][r] - mx) * sc);
      acc[nf][r] = e; s += e;
    }
#pragma unroll
    for (int o = 8; o >= 1; o >>= 1) s += __shfl_xor(s, o);
    const float rinv = 1.f / s;
    const int qrow = qb + wave * 16 + r0 + r;
    u16* prow = probs + (size_t)((b * 16 + h) * 256 + qrow) * 256;
#pragma unroll
    for (int nf = 0; nf < 16; ++nf)
      prow[nf * 16 + cc] = f2bf(acc[nf][r] * rinv);
  }
}

// ---------------------------------------------------------------------------
// A = mean over heads of probs. grid(8192=b*256+q), 256 thr
// ---------------------------------------------------------------------------
__global__ __launch_bounds__(256) void amean(const u16* __restrict__ probs,
                                             float* __restrict__ A) {
  const int bq = blockIdx.x;
  const int b = bq >> 8, q = bq & 255;
  const int t = threadIdx.x;
  float s = 0.f;
#pragma unroll
  for (int h = 0; h < 16; ++h)
    s += bf2f(probs[(size_t)((b * 16 + h) * 256 + q) * 256 + t]);
  A[(size_t)bq * 256 + t] = s * (1.f / 16.f);
}

// ---------------------------------------------------------------------------
// PV: ctx[b,:,h*64:+64] = probs[b,h] @ V[b,h]. grid(16 h, 32 b), 256 thr
// ---------------------------------------------------------------------------
__global__ __launch_bounds__(256) void attn_pv(const u16* __restrict__ qkv,
                                               const u16* __restrict__ probs,
                                               u16* __restrict__ ctx) {
  __shared__ u16 Vs[64 * 256];  // 32KB: [d][kk], swizzled
  const int t = threadIdx.x, lane = t & 63, wave = t >> 6;
  const int h = blockIdx.x, b = blockIdx.y;

#pragma unroll
  for (int p = 0; p < 8; ++p) {
    int idx = p * 2048 + t * 8;
    int kk = idx >> 6, d0 = idx & 63;
    u16x8 vv = *(const u16x8*)(qkv + (size_t)(b * 256 + kk) * 3072 + 2048 + h * 64 + d0);
#pragma unroll
    for (int j = 0; j < 8; ++j) {
      int d = d0 + j;
      int byt = (d * 512 + kk * 2) ^ ((d & 7) << 4);
      *(u16*)((char*)Vs + byt) = vv[j];
    }
  }
  __syncthreads();

  f32x4 acc[4][4] = {};
  const u16* Pb = probs + (size_t)((b * 16 + h) * 256) * 256;
  const int cc = lane & 15, kg = (lane >> 4) * 8;
#pragma unroll
  for (int kt = 0; kt < 8; ++kt) {
    bf16x8 a[4], v[4];
#pragma unroll
    for (int m = 0; m < 4; ++m)
      a[m] = *(const bf16x8*)(Pb + (size_t)(wave * 64 + m * 16 + cc) * 256 + kt * 32 + kg);
#pragma unroll
    for (int n = 0; n < 4; ++n) {
      int d = n * 16 + cc;
      int kk = kt * 32 + kg;
      int byt = (d * 512 + kk * 2) ^ ((d & 7) << 4);
      v[n] = *(const bf16x8*)((const char*)Vs + byt);
    }
#pragma unroll
    for (int m = 0; m < 4; ++m)
#pragma unroll
      for (int n = 0; n < 4; ++n)
        acc[m][n] = __builtin_amdgcn_mfma_f32_16x16x32_bf16(a[m], v[n], acc[m][n], 0, 0, 0);
  }

  const int r0 = (lane >> 4) * 4;
#pragma unroll
  for (int m = 0; m < 4; ++m) {
    const int q = wave * 64 + m * 16 + r0;
#pragma unroll
    for (int n = 0; n < 4; ++n) {
      const int col = h * 64 + n * 16 + cc;
#pragma unroll
      for (int r = 0; r < 4; ++r)
        ctx[(size_t)(b * 256 + q + r) * 1024 + col] = f2bf(acc[m][n][r]);
    }
  }
}

// ---------------------------------------------------------------------------
extern "C" void kernel_launch(void* const* d_in, const int* in_sizes, int n_in,
                              void* d_out, int out_size, void* d_ws, size_t ws_size,
                              hipStream_t stream) {
  const float* X      = (const float*)d_in[0];
  const float* W_qkv  = (const float*)d_in[1];
  const float* b_qkv  = (const float*)d_in[2];
  const float* W_proj = (const float*)d_in[3];
  const float* b_proj = (const float*)d_in[4];
  const float* g1     = (const float*)d_in[5];
  const float* beta1  = (const float*)d_in[6];
  const float* g2     = (const float*)d_in[7];
  const float* beta2  = (const float*)d_in[8];
  const float* W_ff1  = (const float*)d_in[9];
  const float* b_ff1  = (const float*)d_in[10];
  const float* W_ff2  = (const float*)d_in[11];
  const float* b_ff2  = (const float*)d_in[12];

  float* Xout = (float*)d_out;                 // [8192][1024]
  float* Aout = (float*)d_out + 8388608;       // [32][256][256]

  char* ws = (char*)d_ws;
  const size_t MB = 1u << 20;
  u16* xn    = (u16*)(ws + 0);          // 16MB: Xn, then ctx, then X1n
  u16* wqkv  = (u16*)(ws + 16 * MB);    // 6MB [3072][1024]
  u16* wproj = (u16*)(ws + 22 * MB);    // 2MB [1024][1024]
  u16* wff1  = (u16*)(ws + 24 * MB);    // 8MB [4096][1024]
  u16* wff2  = (u16*)(ws + 32 * MB);    // 8MB [1024][4096]
  u16* qkv   = (u16*)(ws + 40 * MB);    // 48MB [8192][3072]
  u16* probs = (u16*)(ws + 88 * MB);    // 64MB [32][16][256][256]; later h
  u16* hbuf  = probs;                   // 64MB [8192][4096]
  float* x1  = (float*)(ws + 152 * MB); // 32MB [8192][1024]  (total 184MB)
  u16* ctx   = xn;                      // reuse region 0 after QKV GEMM
  u16* x1n   = xn;                      // reuse region 0 after proj GEMM

  const dim3 tb(32, 8);
  transpose_cast<<<dim3(96, 32),  tb, 0, stream>>>(W_qkv,  wqkv, 1024, 3072);
  transpose_cast<<<dim3(32, 32),  tb, 0, stream>>>(W_proj, wproj, 1024, 1024);
  transpose_cast<<<dim3(128, 32), tb, 0, stream>>>(W_ff1,  wff1, 1024, 4096);
  transpose_cast<<<dim3(32, 128), tb, 0, stream>>>(W_ff2,  wff2, 4096, 1024);

  layernorm_bf16<<<8192, 256, 0, stream>>>(X, g1, beta1, xn);

  // QKV: 128x128, grid 64x24 = 1536 blocks (3 even rounds at 2 blk/CU).
  gemm_128<0><<<1536, 256, 0, stream>>>(xn, wqkv, b_qkv, nullptr, nullptr, qkv,
                                        8192, 3072, 1024);

  attn_scores<<<dim3(4, 16, 32), 256, 0, stream>>>(qkv, probs);
  amean<<<8192, 256, 0, stream>>>(probs, Aout);
  attn_pv<<<dim3(16, 32), 256, 0, stream>>>(qkv, probs, ctx);

  // proj + residual: grid 64x8 = 512 blocks (1 round).
  gemm_128<1><<<512, 256, 0, stream>>>(ctx, wproj, b_proj, X, x1, nullptr,
                                       8192, 1024, 1024);

  layernorm_bf16<<<8192, 256, 0, stream>>>(x1, g2, beta2, x1n);

  // FF1 + GELU: grid 64x32 = 2048 blocks (4 rounds).
  gemm_128<2><<<2048, 256, 0, stream>>>(x1n, wff1, b_ff1, nullptr, nullptr, hbuf,
                                        8192, 4096, 1024);

  // FF2 + residual: grid 64x8 = 512 blocks (1 round).
  gemm_128<1><<<512, 256, 0, stream>>>(hbuf, wff2, b_ff2, x1, Xout, nullptr,
                                       8192, 1024, 4096);
}